// Round 5
// baseline (160.330 us; speedup 1.0000x reference)
//
#include <hip/hip_runtime.h>
#include <hip/hip_bf16.h>

// Problem constants
#define B_   8
#define T_   8192
#define D_   128
#define K_   64
#define TC   16      // timesteps per chunk (one wave's serial run)
#define GP   136     // LDS pitch (ushorts) for W hi/lo rows
#define MP   72      // sigma-path LDS pitch (ushorts)

typedef float  floatx4  __attribute__((ext_vector_type(4)));
typedef __bf16 bf16x8   __attribute__((ext_vector_type(8)));
typedef unsigned short ushortx8 __attribute__((ext_vector_type(8)));

__device__ inline unsigned short f2bf(float f) {
  unsigned u = __float_as_uint(f);
  u = u + 0x7FFFu + ((u >> 16) & 1u);   // RNE to bf16
  return (unsigned short)(u >> 16);
}
__device__ inline float bf2f(unsigned short h) {
  return __uint_as_float(((unsigned)h) << 16);
}

// ---------------------------------------------------------------------------
// k_zero: flags live in poisoned workspace; zero them strictly before k_mega.
// FL[0..255] = per-block scan flags, FL[256] = sigma-ready flag.
// ---------------------------------------------------------------------------
__global__ __launch_bounds__(512) void k_zero(int* __restrict__ FL) {
  if (threadIdx.x < 257) FL[threadIdx.x] = 0;
}

// ---------------------------------------------------------------------------
// k_mega: everything in one kernel. Grid 256 x 1024 (1 block/CU, 117 KB LDS).
// Block g: batch b = g>>5, time stripe tb = g&31 (256 steps). Wave w owns one
// 16-step chunk, lane = k.
//
//   0. stage W -> bf16 hi/lo LDS (all blocks); block 0 first runs the sigma
//      power iteration inline (tid<256 active, barriers block-uniform) and
//      releases FL[256].
//   1. GEMM: wave w computes its OWN 16x64 V tile via MFMA (identical math
//      to the old k_gemm_sigma GEMM path) -> 4 KB LDS per wave. V never
//      touches HBM (-32 MB round trip, -1 kernel launch).
//   2. poll sigma flag once per block -> invs.
//   3. phase 1 (coefficients cached in regs, u overwrites v in LDS),
//      within-block prefix, BA publish + FL release, wave-0 cross-block
//      compose (R4's 2-fence protocol), phase 3 replay, write out.
// ---------------------------------------------------------------------------
__global__ __launch_bounds__(1024, 4) void k_mega(
    const float* __restrict__ x,  const float* __restrict__ W,
    const float* __restrict__ am, const float* __restrict__ om,
    const float* __restrict__ tm, const float* __restrict__ dtp,
    const float* __restrict__ sr, const float* __restrict__ si,
    const float* __restrict__ traw, const float* __restrict__ bb,
    float* __restrict__ sig, float* __restrict__ BA, int* __restrict__ FL,
    float* __restrict__ out) {
  __shared__ __align__(16) unsigned char smem[117264];
  unsigned short* Wh   = (unsigned short*)smem;            // [64][GP] 17408 B
  unsigned short* Wl   = Wh + 64 * GP;                     // 17408 B -> 34816
  float*          Vt   = (float*)(smem + 34816);           // 16 waves x [16][64] f32 = 65536 -> 100352
  float4*         sAgg = (float4*)(smem + 100352);         // 16x64 = 16384 -> 116736
  float2*         sH   = (float2*)(smem + 116736);         // 512 -> 117248
  float*          sInv = (float*)(smem + 117248);          // 4
  // sigma scratch aliases the Vt region (block 0 only; sigma completes
  // before any Vt write, separated by __syncthreads):
  unsigned short* Ma  = (unsigned short*)(smem + 34816);   // 64*MP ushorts
  unsigned short* Mb  = Ma + 64 * MP;
  float*          red = (float*)(smem + 53248);
  float*          vsh = red + 4;
  int*            jsh = (int*)(vsh + 64);

  const int tid  = threadIdx.x;
  const int lane = tid & 63;
  const int w    = __builtin_amdgcn_readfirstlane(tid >> 6);  // wave 0..15
  const int l15  = lane & 15;
  const int q    = lane >> 4;
  const int g    = blockIdx.x;       // 0..255
  const int b    = g >> 5;
  const int tb   = g & 31;
  const int gb   = g & ~31;

  // ===== block 0: inline sigma (all 1024 threads traverse the barriers) ====
  if (g == 0) {
    const int wv = tid >> 6;         // 0..3 when tid<256
    {
      floatx4 acc[4] = {};
      if (tid < 256) {
        const int arow = 16 * wv + l15;
        for (int s = 0; s < 4; ++s) {
          const int kb = 32 * s + 8 * q;
          float4 a0 = *(const float4*)(W + arow * 128 + kb);
          float4 a1 = *(const float4*)(W + arow * 128 + kb + 4);
          ushortx8 ua;
          ua[0] = f2bf(a0.x); ua[1] = f2bf(a0.y); ua[2] = f2bf(a0.z); ua[3] = f2bf(a0.w);
          ua[4] = f2bf(a1.x); ua[5] = f2bf(a1.y); ua[6] = f2bf(a1.z); ua[7] = f2bf(a1.w);
          bf16x8 av = __builtin_bit_cast(bf16x8, ua);
          for (int tn = 0; tn < 4; ++tn) {
            const int brow = 16 * tn + l15;
            float4 b0 = *(const float4*)(W + brow * 128 + kb);
            float4 b1 = *(const float4*)(W + brow * 128 + kb + 4);
            ushortx8 ub;
            ub[0] = f2bf(b0.x); ub[1] = f2bf(b0.y); ub[2] = f2bf(b0.z); ub[3] = f2bf(b0.w);
            ub[4] = f2bf(b1.x); ub[5] = f2bf(b1.y); ub[6] = f2bf(b1.z); ub[7] = f2bf(b1.w);
            bf16x8 bv = __builtin_bit_cast(bf16x8, ub);
            acc[tn] = __builtin_amdgcn_mfma_f32_16x16x32_bf16(av, bv, acc[tn], 0, 0, 0);
          }
        }
        float mx = 0.f;
        for (int tn = 0; tn < 4; ++tn)
          for (int r = 0; r < 4; ++r) mx = fmaxf(mx, fabsf(acc[tn][r]));
        for (int off = 32; off; off >>= 1) mx = fmaxf(mx, __shfl_xor(mx, off));
        if (lane == 0) red[wv] = mx;
      }
      __syncthreads();
      if (tid < 256) {
        float gm  = fmaxf(fmaxf(red[0], red[1]), fmaxf(red[2], red[3]));
        float inv = 1.f / gm;
        for (int tn = 0; tn < 4; ++tn)
          for (int r = 0; r < 4; ++r)
            Ma[(16 * wv + 4 * q + r) * MP + 16 * tn + l15] = f2bf(acc[tn][r] * inv);
      }
      __syncthreads();
    }

    unsigned short* src = Ma;
    unsigned short* dst = Mb;
    for (int it = 0; it < 8; ++it) {
      if (tid < 256) {
        floatx4 f[4] = {};
        for (int s = 0; s < 2; ++s) {
          const int kb = 32 * s + 8 * q;
          uint4 ua4 = *(const uint4*)(src + (16 * wv + l15) * MP + kb);
          bf16x8 av = __builtin_bit_cast(bf16x8, ua4);
          for (int tn = 0; tn < 4; ++tn) {
            const int n = 16 * tn + l15;
            ushortx8 ub;
            #pragma unroll
            for (int j = 0; j < 8; ++j) ub[j] = src[(kb + j) * MP + n];
            bf16x8 bv = __builtin_bit_cast(bf16x8, ub);
            f[tn] = __builtin_amdgcn_mfma_f32_16x16x32_bf16(av, bv, f[tn], 0, 0, 0);
          }
        }
        float m2 = 0.f;
        for (int tn = 0; tn < 4; ++tn)
          for (int r = 0; r < 4; ++r) m2 = fmaxf(m2, fabsf(f[tn][r]));
        for (int off = 32; off; off >>= 1) m2 = fmaxf(m2, __shfl_xor(m2, off));
        if (lane == 0) red[wv] = m2;
        __syncthreads();
        float gm2  = fmaxf(fmaxf(red[0], red[1]), fmaxf(red[2], red[3]));
        float inv2 = 1.f / gm2;
        for (int tn = 0; tn < 4; ++tn)
          for (int r = 0; r < 4; ++r)
            dst[(16 * wv + 4 * q + r) * MP + 16 * tn + l15] = f2bf(f[tn][r] * inv2);
      } else {
        __syncthreads();
      }
      __syncthreads();
      unsigned short* t2 = src; src = dst; dst = t2;
    }

    if (tid == 0) {
      int jb = 0; float best = -1.f;
      for (int j = 0; j < 64; ++j) {
        float dv = bf2f(src[j * MP + j]);
        if (dv > best) { best = dv; jb = j; }
      }
      *jsh = jb;
    }
    __syncthreads();
    if (tid < 64) vsh[tid] = bf2f(src[tid * MP + *jsh]);
    __syncthreads();
    if (tid < 64) {
      float wa = 0.f, wb2 = 0.f;
      for (int i = 0; i < 64; ++i) {
        float vi = vsh[i];
        wa  = fmaf(W[i * 128 + lane], vi, wa);
        wb2 = fmaf(W[i * 128 + 64 + lane], vi, wb2);
      }
      float num = wa * wa + wb2 * wb2;
      float den = vsh[lane] * vsh[lane];
      for (int off = 32; off; off >>= 1) {
        num += __shfl_xor(num, off);
        den += __shfl_xor(den, off);
      }
      if (lane == 0) sig[0] = 1.f / sqrtf(num / den);
    }
    if (tid == 0) {
      __threadfence();   // sig[0] (written by this thread) -> visible
      __hip_atomic_store(&FL[256], 1, __ATOMIC_RELEASE, __HIP_MEMORY_SCOPE_AGENT);
    }
    __syncthreads();     // sigma scratch dead before Vt reuse below
  }

  // ===== stage W -> bf16 hi/lo in LDS (all blocks, 1024 threads) ===========
  #pragma unroll
  for (int j = 0; j < 2; ++j) {
    const int v = tid + 1024 * j;          // float4 index, 0..2047
    float4 w4 = ((const float4*)W)[v];
    const int e = v * 4;
    const int row = e >> 7, col = e & 127;
    float a[4] = {w4.x, w4.y, w4.z, w4.w};
    unsigned short h[4], l[4];
    #pragma unroll
    for (int i = 0; i < 4; ++i) {
      h[i] = f2bf(a[i]);
      l[i] = f2bf(a[i] - bf2f(h[i]));
    }
    unsigned hp0 = (unsigned)h[0] | ((unsigned)h[1] << 16);
    unsigned hp1 = (unsigned)h[2] | ((unsigned)h[3] << 16);
    unsigned lp0 = (unsigned)l[0] | ((unsigned)l[1] << 16);
    unsigned lp1 = (unsigned)l[2] | ((unsigned)l[3] << 16);
    *(uint2*)(Wh + row * GP + col) = make_uint2(hp0, hp1);
    *(uint2*)(Wl + row * GP + col) = make_uint2(lp0, lp1);
  }
  __syncthreads();

  // ===== GEMM: wave w computes its own 16x64 V tile =========================
  const int bt0 = b * T_ + tb * 256 + w * TC;   // first timestep row of chunk
  float* Vw = Vt + w * 1024;                    // this wave's [16][64] tile
  {
    floatx4 acc[4] = {};
    #pragma unroll
    for (int s = 0; s < 4; ++s) {
      const float* xp = x + ((size_t)(bt0 + l15) << 7) + 32 * s + 8 * q;
      float4 x0 = *(const float4*)xp;
      float4 x1 = *(const float4*)(xp + 4);
      float xs8[8] = {x0.x, x0.y, x0.z, x0.w, x1.x, x1.y, x1.z, x1.w};
      ushortx8 uh, ul;
      #pragma unroll
      for (int j = 0; j < 8; ++j) {
        unsigned short h = f2bf(xs8[j]);
        uh[j] = h;
        ul[j] = f2bf(xs8[j] - bf2f(h));
      }
      bf16x8 ah = __builtin_bit_cast(bf16x8, uh);
      bf16x8 al = __builtin_bit_cast(bf16x8, ul);
      #pragma unroll
      for (int t = 0; t < 4; ++t) {
        const unsigned short* bp = Wh + (16 * t + l15) * GP + 32 * s + 8 * q;
        bf16x8 bh = __builtin_bit_cast(bf16x8, *(const uint4*)bp);
        const unsigned short* bq = Wl + (16 * t + l15) * GP + 32 * s + 8 * q;
        bf16x8 bl = __builtin_bit_cast(bf16x8, *(const uint4*)bq);
        acc[t] = __builtin_amdgcn_mfma_f32_16x16x32_bf16(ah, bh, acc[t], 0, 0, 0);
        acc[t] = __builtin_amdgcn_mfma_f32_16x16x32_bf16(al, bh, acc[t], 0, 0, 0);
        acc[t] = __builtin_amdgcn_mfma_f32_16x16x32_bf16(ah, bl, acc[t], 0, 0, 0);
      }
    }
    // C layout: col = 16t+l15, row(within tile) = 4q+r
    #pragma unroll
    for (int t = 0; t < 4; ++t)
      #pragma unroll
      for (int r = 0; r < 4; ++r)
        Vw[(4 * q + r) * 64 + 16 * t + l15] = acc[t][r];
    // NOTE: Vw is read only by this same wave -> no barrier needed.
  }

  // ===== sigma ready -> invs (one poll per block) ===========================
  if (tid == 0) {
    while (__hip_atomic_load(&FL[256], __ATOMIC_RELAXED,
                             __HIP_MEMORY_SCOPE_AGENT) == 0)
      __builtin_amdgcn_s_sleep(2);
    __threadfence();
    sInv[0] = sig[0];
  }
  __syncthreads();
  const float invs = sInv[0];

  // ===== phase 1: per-step coefficients (regs), u overwrites v in LDS ======
  const float tau    = log1pf(__expf(traw[0])) + 1e-3f;
  const float alpha0 = (log1pf(__expf(sr[lane])) + 1e-6f) * tau;
  const float omega0 = si[lane] * tau;
  const float bk     = bb[lane];

  const float* pa = am + (size_t)bt0 * 64 + lane;
  const float* po = om + (size_t)bt0 * 64 + lane;
  float ca[TC], co[TC], ctm[TC], cdt[TC];
  #pragma unroll
  for (int t = 0; t < TC; ++t) {
    ca[t] = pa[64 * t];
    co[t] = po[64 * t];
  }
  #pragma unroll
  for (int t = 0; t < TC; ++t) {
    ctm[t] = tm[bt0 + t];      // wave-uniform -> scalar loads
    cdt[t] = dtp[bt0 + t];
  }
  __builtin_amdgcn_sched_barrier(0);

  float Ar = 1.f, Ai = 0.f, Ur = 0.f, Ui = 0.f;
  #pragma unroll
  for (int t = 0; t < TC; ++t) {
    float tmv = ctm[t];
    float dtv = cdt[t];
    float alpha = alpha0 * __expf(ca[t] + tmv);
    float omega = omega0 * __expf(co[t] + tmv);
    float rho = __expf(-alpha * dtv);
    float th  = omega * dtv;
    float th2 = th * th;
    float st  = th * fmaf(th2, -0.16666667f, 1.f);  // |theta|<1.6e-3: exact
    float ct  = fmaf(th2, -0.5f, 1.f);
    float ar  = rho * ct, ai = rho * st;
    float u   = fmaf(Vw[t * 64 + lane], invs, bk);
    Vw[t * 64 + lane] = u;                          // phase 3 reads u back
    ca[t] = ar; co[t] = ai;
    float nUr = fmaf(ar, Ur, fmaf(-ai, Ui, u));
    float nUi = fmaf(ar, Ui, ai * Ur);
    Ur = nUr; Ui = nUi;
    float nAr = fmaf(ar, Ar, -ai * Ai);
    float nAi = fmaf(ar, Ai, ai * Ar);
    Ar = nAr; Ai = nAi;
  }
  sAgg[w * 64 + lane] = make_float4(Ar, Ai, Ur, Ui);
  __syncthreads();

  // ---- exclusive within-block prefix over chunks 0..w-1 (branch-free) ----
  float Er = 1.f, Ei = 0.f, Fr = 0.f, Fi = 0.f;
  #pragma unroll
  for (int j = 0; j < 15; ++j) {
    float4 a = sAgg[j * 64 + lane];
    bool p = (j < w);
    float ax = p ? a.x : 1.f;
    float ay = p ? a.y : 0.f;
    float az = p ? a.z : 0.f;
    float aw_ = p ? a.w : 0.f;
    float nEr = ax * Er - ay * Ei;
    float nEi = ax * Ei + ay * Er;
    float nFr = fmaf(ax, Fr, fmaf(-ay, Fi, az));
    float nFi = fmaf(ax, Fi, fmaf(ay, Fr, aw_));
    Er = nEr; Ei = nEi; Fr = nFr; Fi = nFi;
  }

  // ---- wave 15 publishes block aggregate; single release fence ----
  if (w == 15) {
    float bAr = Ar * Er - Ai * Ei;
    float bAi = Ar * Ei + Ai * Er;
    float bUr = fmaf(Ar, Fr, fmaf(-Ai, Fi, Ur));
    float bUi = fmaf(Ar, Fi, fmaf(Ai, Fr, Ui));
    *(float4*)(BA + (size_t)(g * 64 + lane) * 4) = make_float4(bAr, bAi, bUr, bUi);
  }
  __syncthreads();               // BA stores drained before the fence
  if (tid == 0) {
    __threadfence();
    __hip_atomic_store(&FL[g], 1, __ATOMIC_RELEASE, __HIP_MEMORY_SCOPE_AGENT);
  }

  // ---- phase 2: wave 0 polls (relaxed), one acquire fence, composes H ----
  if (w == 0) {
    if (lane < tb) {
      while (__hip_atomic_load(&FL[gb + lane], __ATOMIC_RELAXED,
                               __HIP_MEMORY_SCOPE_AGENT) == 0)
        __builtin_amdgcn_s_sleep(2);
    }
    __threadfence();
    float Hr = 0.f, Hi = 0.f;
    for (int j0 = 0; j0 < tb; j0 += 8) {
      float4 a[8];
      #pragma unroll
      for (int j = 0; j < 8; ++j) {
        if (j0 + j < tb)
          a[j] = *(const float4*)(BA + (size_t)((gb + j0 + j) * 64 + lane) * 4);
        else
          a[j] = make_float4(1.f, 0.f, 0.f, 0.f);
      }
      #pragma unroll
      for (int j = 0; j < 8; ++j) {
        float nHr = fmaf(a[j].x, Hr, fmaf(-a[j].y, Hi, a[j].z));
        float nHi = fmaf(a[j].x, Hi, fmaf(a[j].y, Hr, a[j].w));
        Hr = nHr; Hi = nHi;
      }
    }
    sH[lane] = make_float2(Hr, Hi);
  }
  __syncthreads();

  float2 h = sH[lane];
  float zr = fmaf(Er, h.x, fmaf(-Ei, h.y, Fr));
  float zi = fmaf(Er, h.y, fmaf(Ei, h.x, Fi));

  // ===== phase 3: replay from regs + LDS u, write out ======================
  float* outp = out + (size_t)bt0 * 128 + lane;
  #pragma unroll
  for (int t = 0; t < TC; ++t) {
    float u  = Vw[t * 64 + lane];
    float nr = fmaf(ca[t], zr, fmaf(-co[t], zi, u));
    float ni = fmaf(ca[t], zi, co[t] * zr);
    zr = nr; zi = ni;
    outp[0]  = zr;     // C
    outp[64] = zi;     // S
    outp += 128;
  }
}

// ---------------------------------------------------------------------------
extern "C" void kernel_launch(void* const* d_in, const int* in_sizes, int n_in,
                              void* d_out, int out_size, void* d_ws, size_t ws_size,
                              hipStream_t stream) {
  (void)in_sizes; (void)n_in; (void)out_size; (void)ws_size;
  const float* x    = (const float*)d_in[0];
  const float* dtp  = (const float*)d_in[1];
  const float* amod = (const float*)d_in[2];
  const float* omod = (const float*)d_in[3];
  const float* tmod = (const float*)d_in[4];
  const float* srr  = (const float*)d_in[5];
  const float* sim  = (const float*)d_in[6];
  const float* traw = (const float*)d_in[7];
  const float* W    = (const float*)d_in[8];
  const float* bb   = (const float*)d_in[9];
  float* out = (float*)d_out;
  float* ws  = (float*)d_ws;

  float* sig = ws;                                   // [16]
  float* BA  = ws + 16;                              // 256*64*4 = 65,536 floats
  int*   FL  = (int*)(BA + 256 * 64 * 4);            // [257]: 256 scan + 1 sigma

  k_zero<<<1, 512, 0, stream>>>(FL);
  k_mega<<<256, 1024, 0, stream>>>(x, W, amod, omod, tmod, dtp, srr, sim,
                                   traw, bb, sig, BA, FL, out);
}

// Round 8
// 159.203 us; speedup vs baseline: 1.0071x; 1.0071x over previous
//
#include <hip/hip_runtime.h>
#include <hip/hip_bf16.h>

// Problem constants
#define B_   8
#define T_   8192
#define D_   128
#define K_   64
#define TC   16      // timesteps per chunk (one wave's serial run)
#define GP   136     // LDS pitch (ushorts) for W hi/lo rows
#define MP   72      // sigma-path LDS pitch (ushorts)

typedef float  floatx4  __attribute__((ext_vector_type(4)));
typedef __bf16 bf16x8   __attribute__((ext_vector_type(8)));
typedef unsigned short ushortx8 __attribute__((ext_vector_type(8)));

__device__ inline unsigned short f2bf(float f) {
  unsigned u = __float_as_uint(f);
  u = u + 0x7FFFu + ((u >> 16) & 1u);   // RNE to bf16
  return (unsigned short)(u >> 16);
}
__device__ inline float bf2f(unsigned short h) {
  return __uint_as_float(((unsigned)h) << 16);
}

// ---------------------------------------------------------------------------
// k_zero: flags live in poisoned workspace; zero them strictly before k_mega.
// FL[0..255] = per-block scan flags, FL[256] = sigma-ready flag.
// ---------------------------------------------------------------------------
__global__ __launch_bounds__(512) void k_zero(int* __restrict__ FL) {
  if (threadIdx.x < 257) FL[threadIdx.x] = 0;
}

// ---------------------------------------------------------------------------
// k_mega v4 (R8): R5's PASSING structure verbatim (single-U scan, sigma on
// block 0, sigma gate before phase 1b, BA pitch 4, R4 2-fence protocol).
// R6/R7's dual-accumulator + sigma-relocation rounds both failed with
// err ~ |state| (cause not identified by inspection) -> fully reverted.
// This round only shrinks SIGMA'S DURATION (the measured ~50us serial gate):
//   - power-iteration loop widened 4 -> 16 waves, bitwise-identical results
//     (wave w owns tile (w>>2, w&3); same fragments, same normalization max)
//   - final num/den matvec parallelized 64 -> 1024 threads (rounding-neutral
//     reassociation only; delta-sigma ~1e-7 relative)
//   - serial diag argmax kept verbatim
// ---------------------------------------------------------------------------
__global__ __launch_bounds__(1024, 4) void k_mega(
    const float* __restrict__ x,  const float* __restrict__ W,
    const float* __restrict__ am, const float* __restrict__ om,
    const float* __restrict__ tm, const float* __restrict__ dtp,
    const float* __restrict__ sr, const float* __restrict__ si,
    const float* __restrict__ traw, const float* __restrict__ bb,
    float* __restrict__ sig, float* __restrict__ BA, int* __restrict__ FL,
    float* __restrict__ out) {
  __shared__ __align__(16) unsigned char smem[117264];
  unsigned short* Wh   = (unsigned short*)smem;            // [64][GP] -> 34816
  unsigned short* Wl   = Wh + 64 * GP;
  float*          Vt   = (float*)(smem + 34816);           // 16 x [16][64] f32 -> 100352
  float4*         sAgg = (float4*)(smem + 100352);         // 16x64 -> 116736
  float2*         sH   = (float2*)(smem + 116736);         // 512 -> 117248
  float*          sInv = (float*)(smem + 117248);          // 4
  // sigma scratch aliases the Vt region (block 0 only; done before Vt use)
  unsigned short* Ma   = (unsigned short*)(smem + 34816);  // 64*MP ushorts
  unsigned short* Mb   = Ma + 64 * MP;                     // ends at 53248
  float*          red  = (float*)(smem + 53248);           // [16]
  float*          vsh  = red + 16;                         // [64]
  int*            jsh  = (int*)(vsh + 64);                 // [1] -> 53572
  float*          pm   = (float*)(smem + 53584);           // [8][128] partials
  float*          col2 = pm + 1024;                        // [128] -> ends 58192

  const int tid  = threadIdx.x;
  const int lane = tid & 63;
  const int w    = __builtin_amdgcn_readfirstlane(tid >> 6);  // wave 0..15
  const int l15  = lane & 15;
  const int q    = lane >> 4;
  const int g    = blockIdx.x;       // 0..255
  const int b    = g >> 5;
  const int tb   = g & 31;
  const int gb   = g & ~31;

  // ===== block 0: inline sigma (all 1024 threads traverse the barriers) ====
  if (g == 0) {
    const int wv = tid >> 6;         // 0..3 when tid<256
    {
      floatx4 acc[4] = {};
      if (tid < 256) {
        const int arow = 16 * wv + l15;
        for (int s = 0; s < 4; ++s) {
          const int kb = 32 * s + 8 * q;
          float4 a0 = *(const float4*)(W + arow * 128 + kb);
          float4 a1 = *(const float4*)(W + arow * 128 + kb + 4);
          ushortx8 ua;
          ua[0] = f2bf(a0.x); ua[1] = f2bf(a0.y); ua[2] = f2bf(a0.z); ua[3] = f2bf(a0.w);
          ua[4] = f2bf(a1.x); ua[5] = f2bf(a1.y); ua[6] = f2bf(a1.z); ua[7] = f2bf(a1.w);
          bf16x8 av = __builtin_bit_cast(bf16x8, ua);
          for (int tn = 0; tn < 4; ++tn) {
            const int brow = 16 * tn + l15;
            float4 b0 = *(const float4*)(W + brow * 128 + kb);
            float4 b1 = *(const float4*)(W + brow * 128 + kb + 4);
            ushortx8 ub;
            ub[0] = f2bf(b0.x); ub[1] = f2bf(b0.y); ub[2] = f2bf(b0.z); ub[3] = f2bf(b0.w);
            ub[4] = f2bf(b1.x); ub[5] = f2bf(b1.y); ub[6] = f2bf(b1.z); ub[7] = f2bf(b1.w);
            bf16x8 bv = __builtin_bit_cast(bf16x8, ub);
            acc[tn] = __builtin_amdgcn_mfma_f32_16x16x32_bf16(av, bv, acc[tn], 0, 0, 0);
          }
        }
        float mx = 0.f;
        for (int tn = 0; tn < 4; ++tn)
          for (int r = 0; r < 4; ++r) mx = fmaxf(mx, fabsf(acc[tn][r]));
        for (int off = 32; off; off >>= 1) mx = fmaxf(mx, __shfl_xor(mx, off));
        if (lane == 0) red[wv] = mx;
      }
      __syncthreads();
      if (tid < 256) {
        float gm  = fmaxf(fmaxf(red[0], red[1]), fmaxf(red[2], red[3]));
        float inv = 1.f / gm;
        for (int tn = 0; tn < 4; ++tn)
          for (int r = 0; r < 4; ++r)
            Ma[(16 * wv + 4 * q + r) * MP + 16 * tn + l15] = f2bf(acc[tn][r] * inv);
      }
      __syncthreads();
    }

    // ---- 8 squaring iterations, 16 waves (bitwise-identical to 4-wave) ----
    unsigned short* src = Ma;
    unsigned short* dst = Mb;
    const int tmw = w >> 2;          // row tile of this wave
    const int tnw = w & 3;           // col tile of this wave
    for (int it = 0; it < 8; ++it) {
      floatx4 f = {};
      for (int s = 0; s < 2; ++s) {
        const int kb = 32 * s + 8 * q;
        uint4 ua4 = *(const uint4*)(src + (16 * tmw + l15) * MP + kb);
        bf16x8 av = __builtin_bit_cast(bf16x8, ua4);
        const int n = 16 * tnw + l15;
        ushortx8 ub;
        #pragma unroll
        for (int j = 0; j < 8; ++j) ub[j] = src[(kb + j) * MP + n];
        bf16x8 bv = __builtin_bit_cast(bf16x8, ub);
        f = __builtin_amdgcn_mfma_f32_16x16x32_bf16(av, bv, f, 0, 0, 0);
      }
      float m2 = fmaxf(fmaxf(fabsf(f[0]), fabsf(f[1])),
                       fmaxf(fabsf(f[2]), fabsf(f[3])));
      for (int off = 32; off; off >>= 1) m2 = fmaxf(m2, __shfl_xor(m2, off));
      if (lane == 0) red[w] = m2;
      __syncthreads();
      {
        float gm2 = red[0];
        #pragma unroll
        for (int k = 1; k < 16; ++k) gm2 = fmaxf(gm2, red[k]);
        float inv2 = 1.f / gm2;
        #pragma unroll
        for (int r = 0; r < 4; ++r)
          dst[(16 * tmw + 4 * q + r) * MP + 16 * tnw + l15] = f2bf(f[r] * inv2);
      }
      __syncthreads();
      unsigned short* t2 = src; src = dst; dst = t2;
    }

    // serial diag argmax (R5 verbatim)
    if (tid == 0) {
      int jb = 0; float best = -1.f;
      for (int j = 0; j < 64; ++j) {
        float dv = bf2f(src[j * MP + j]);
        if (dv > best) { best = dv; jb = j; }
      }
      *jsh = jb;
    }
    __syncthreads();
    if (tid < 64) vsh[tid] = bf2f(src[tid * MP + *jsh]);
    __syncthreads();

    // ---- parallel matvec: S[c] = sum_i W[i*128+c]*vsh[i], 1024 threads ----
    {
      const int c = tid & 127;
      const int p = tid >> 7;        // 0..7 -> i in [8p, 8p+8)
      float part = 0.f;
      #pragma unroll
      for (int i = 0; i < 8; ++i)
        part = fmaf(W[(8 * p + i) * 128 + c], vsh[8 * p + i], part);
      pm[p * 128 + c] = part;
    }
    __syncthreads();
    if (tid < 128) {
      float s = 0.f;
      #pragma unroll
      for (int p2 = 0; p2 < 8; ++p2) s += pm[p2 * 128 + tid];
      col2[tid] = s * s;
    }
    __syncthreads();
    if (tid < 64) {
      float num = col2[tid] + col2[tid + 64];
      float den = vsh[tid] * vsh[tid];
      for (int off = 32; off; off >>= 1) {
        num += __shfl_xor(num, off);
        den += __shfl_xor(den, off);
      }
      if (tid == 0) sig[0] = 1.f / sqrtf(num / den);
    }
    if (tid == 0) {
      __threadfence();   // sig[0] (written by this thread) -> visible
      __hip_atomic_store(&FL[256], 1, __ATOMIC_RELEASE, __HIP_MEMORY_SCOPE_AGENT);
    }
    __syncthreads();     // sigma scratch dead before Vt reuse below
  }

  // ===== stage W -> bf16 hi/lo in LDS (all blocks, 1024 threads) ===========
  #pragma unroll
  for (int j = 0; j < 2; ++j) {
    const int v = tid + 1024 * j;          // float4 index, 0..2047
    float4 w4 = ((const float4*)W)[v];
    const int e = v * 4;
    const int row = e >> 7, col = e & 127;
    float a[4] = {w4.x, w4.y, w4.z, w4.w};
    unsigned short h[4], l[4];
    #pragma unroll
    for (int i = 0; i < 4; ++i) {
      h[i] = f2bf(a[i]);
      l[i] = f2bf(a[i] - bf2f(h[i]));
    }
    unsigned hp0 = (unsigned)h[0] | ((unsigned)h[1] << 16);
    unsigned hp1 = (unsigned)h[2] | ((unsigned)h[3] << 16);
    unsigned lp0 = (unsigned)l[0] | ((unsigned)l[1] << 16);
    unsigned lp1 = (unsigned)l[2] | ((unsigned)l[3] << 16);
    *(uint2*)(Wh + row * GP + col) = make_uint2(hp0, hp1);
    *(uint2*)(Wl + row * GP + col) = make_uint2(lp0, lp1);
  }
  __syncthreads();

  const int bt0 = b * T_ + tb * 256 + w * TC;   // first timestep row of chunk

  // ===== GEMM: wave w computes its own 16x64 V tile ========================
  float* Vw = Vt + w * 1024;                    // this wave's [16][64] tile
  {
    floatx4 acc[4] = {};
    #pragma unroll
    for (int s = 0; s < 4; ++s) {
      const float* xp = x + ((size_t)(bt0 + l15) << 7) + 32 * s + 8 * q;
      float4 x0 = *(const float4*)xp;
      float4 x1 = *(const float4*)(xp + 4);
      float xs8[8] = {x0.x, x0.y, x0.z, x0.w, x1.x, x1.y, x1.z, x1.w};
      ushortx8 uh, ul;
      #pragma unroll
      for (int j = 0; j < 8; ++j) {
        unsigned short h = f2bf(xs8[j]);
        uh[j] = h;
        ul[j] = f2bf(xs8[j] - bf2f(h));
      }
      bf16x8 ah = __builtin_bit_cast(bf16x8, uh);
      bf16x8 al = __builtin_bit_cast(bf16x8, ul);
      #pragma unroll
      for (int t = 0; t < 4; ++t) {
        const unsigned short* bp = Wh + (16 * t + l15) * GP + 32 * s + 8 * q;
        bf16x8 bh = __builtin_bit_cast(bf16x8, *(const uint4*)bp);
        const unsigned short* bq = Wl + (16 * t + l15) * GP + 32 * s + 8 * q;
        bf16x8 bl = __builtin_bit_cast(bf16x8, *(const uint4*)bq);
        acc[t] = __builtin_amdgcn_mfma_f32_16x16x32_bf16(ah, bh, acc[t], 0, 0, 0);
        acc[t] = __builtin_amdgcn_mfma_f32_16x16x32_bf16(al, bh, acc[t], 0, 0, 0);
        acc[t] = __builtin_amdgcn_mfma_f32_16x16x32_bf16(ah, bl, acc[t], 0, 0, 0);
      }
    }
    // C layout: col = 16t+l15, row(within tile) = 4q+r
    #pragma unroll
    for (int t = 0; t < 4; ++t)
      #pragma unroll
      for (int r = 0; r < 4; ++r)
        Vw[(4 * q + r) * 64 + 16 * t + l15] = acc[t][r];
    // Vw is read only by this same wave -> no barrier needed.
  }

  // ===== sigma ready -> invs (one poll per block; R5 verbatim) =============
  if (tid == 0) {
    while (__hip_atomic_load(&FL[256], __ATOMIC_RELAXED,
                             __HIP_MEMORY_SCOPE_AGENT) == 0)
      __builtin_amdgcn_s_sleep(2);
    __threadfence();
    sInv[0] = sig[0];
  }
  __syncthreads();
  const float invs = sInv[0];

  // ===== phase 1: per-step coefficients (regs), u overwrites v in LDS ======
  const float tau    = log1pf(__expf(traw[0])) + 1e-3f;
  const float alpha0 = (log1pf(__expf(sr[lane])) + 1e-6f) * tau;
  const float omega0 = si[lane] * tau;
  const float bk     = bb[lane];

  const float* pa = am + (size_t)bt0 * 64 + lane;
  const float* po = om + (size_t)bt0 * 64 + lane;
  float ca[TC], co[TC], ctm[TC], cdt[TC];
  #pragma unroll
  for (int t = 0; t < TC; ++t) {
    ca[t] = pa[64 * t];
    co[t] = po[64 * t];
  }
  #pragma unroll
  for (int t = 0; t < TC; ++t) {
    ctm[t] = tm[bt0 + t];      // wave-uniform -> scalar loads
    cdt[t] = dtp[bt0 + t];
  }
  __builtin_amdgcn_sched_barrier(0);

  float Ar = 1.f, Ai = 0.f, Ur = 0.f, Ui = 0.f;
  #pragma unroll
  for (int t = 0; t < TC; ++t) {
    float tmv = ctm[t];
    float dtv = cdt[t];
    float alpha = alpha0 * __expf(ca[t] + tmv);
    float omega = omega0 * __expf(co[t] + tmv);
    float rho = __expf(-alpha * dtv);
    float th  = omega * dtv;
    float th2 = th * th;
    float st  = th * fmaf(th2, -0.16666667f, 1.f);  // |theta|<1.6e-3: exact
    float ct  = fmaf(th2, -0.5f, 1.f);
    float ar  = rho * ct, ai = rho * st;
    float u   = fmaf(Vw[t * 64 + lane], invs, bk);
    Vw[t * 64 + lane] = u;                          // phase 3 reads u back
    ca[t] = ar; co[t] = ai;
    float nUr = fmaf(ar, Ur, fmaf(-ai, Ui, u));
    float nUi = fmaf(ar, Ui, ai * Ur);
    Ur = nUr; Ui = nUi;
    float nAr = fmaf(ar, Ar, -ai * Ai);
    float nAi = fmaf(ar, Ai, ai * Ar);
    Ar = nAr; Ai = nAi;
  }
  sAgg[w * 64 + lane] = make_float4(Ar, Ai, Ur, Ui);
  __syncthreads();

  // ---- exclusive within-block prefix over chunks 0..w-1 (branch-free) ----
  float Er = 1.f, Ei = 0.f, Fr = 0.f, Fi = 0.f;
  #pragma unroll
  for (int j = 0; j < 15; ++j) {
    float4 a = sAgg[j * 64 + lane];
    bool p = (j < w);
    float ax = p ? a.x : 1.f;
    float ay = p ? a.y : 0.f;
    float az = p ? a.z : 0.f;
    float aw_ = p ? a.w : 0.f;
    float nEr = ax * Er - ay * Ei;
    float nEi = ax * Ei + ay * Er;
    float nFr = fmaf(ax, Fr, fmaf(-ay, Fi, az));
    float nFi = fmaf(ax, Fi, fmaf(ay, Fr, aw_));
    Er = nEr; Ei = nEi; Fr = nFr; Fi = nFi;
  }

  // ---- wave 15 publishes block aggregate; single release fence ----
  if (w == 15) {
    float bAr = Ar * Er - Ai * Ei;
    float bAi = Ar * Ei + Ai * Er;
    float bUr = fmaf(Ar, Fr, fmaf(-Ai, Fi, Ur));
    float bUi = fmaf(Ar, Fi, fmaf(Ai, Fr, Ui));
    *(float4*)(BA + (size_t)(g * 64 + lane) * 4) = make_float4(bAr, bAi, bUr, bUi);
  }
  __syncthreads();               // BA stores drained before the fence
  if (tid == 0) {
    __threadfence();
    __hip_atomic_store(&FL[g], 1, __ATOMIC_RELEASE, __HIP_MEMORY_SCOPE_AGENT);
  }

  // ---- phase 2: wave 0 polls (relaxed), one acquire fence, composes H ----
  if (w == 0) {
    if (lane < tb) {
      while (__hip_atomic_load(&FL[gb + lane], __ATOMIC_RELAXED,
                               __HIP_MEMORY_SCOPE_AGENT) == 0)
        __builtin_amdgcn_s_sleep(2);
    }
    __threadfence();
    float Hr = 0.f, Hi = 0.f;
    for (int j0 = 0; j0 < tb; j0 += 8) {
      float4 a[8];
      #pragma unroll
      for (int j = 0; j < 8; ++j) {
        if (j0 + j < tb)
          a[j] = *(const float4*)(BA + (size_t)((gb + j0 + j) * 64 + lane) * 4);
        else
          a[j] = make_float4(1.f, 0.f, 0.f, 0.f);
      }
      #pragma unroll
      for (int j = 0; j < 8; ++j) {
        float nHr = fmaf(a[j].x, Hr, fmaf(-a[j].y, Hi, a[j].z));
        float nHi = fmaf(a[j].x, Hi, fmaf(a[j].y, Hr, a[j].w));
        Hr = nHr; Hi = nHi;
      }
    }
    sH[lane] = make_float2(Hr, Hi);
  }
  __syncthreads();

  float2 h = sH[lane];
  float zr = fmaf(Er, h.x, fmaf(-Ei, h.y, Fr));
  float zi = fmaf(Er, h.y, fmaf(Ei, h.x, Fi));

  // ===== phase 3: replay from regs + LDS u, write out ======================
  float* outp = out + (size_t)bt0 * 128 + lane;
  #pragma unroll
  for (int t = 0; t < TC; ++t) {
    float u  = Vw[t * 64 + lane];
    float nr = fmaf(ca[t], zr, fmaf(-co[t], zi, u));
    float ni = fmaf(ca[t], zi, co[t] * zr);
    zr = nr; zi = ni;
    outp[0]  = zr;     // C
    outp[64] = zi;     // S
    outp += 128;
  }
}

// ---------------------------------------------------------------------------
extern "C" void kernel_launch(void* const* d_in, const int* in_sizes, int n_in,
                              void* d_out, int out_size, void* d_ws, size_t ws_size,
                              hipStream_t stream) {
  (void)in_sizes; (void)n_in; (void)out_size; (void)ws_size;
  const float* x    = (const float*)d_in[0];
  const float* dtp  = (const float*)d_in[1];
  const float* amod = (const float*)d_in[2];
  const float* omod = (const float*)d_in[3];
  const float* tmod = (const float*)d_in[4];
  const float* srr  = (const float*)d_in[5];
  const float* sim  = (const float*)d_in[6];
  const float* traw = (const float*)d_in[7];
  const float* W    = (const float*)d_in[8];
  const float* bb   = (const float*)d_in[9];
  float* out = (float*)d_out;
  float* ws  = (float*)d_ws;

  float* sig = ws;                                   // [16]
  float* BA  = ws + 16;                              // 256*64*4 floats
  int*   FL  = (int*)(BA + 256 * 64 * 4);            // [257]: 256 scan + 1 sigma

  k_zero<<<1, 512, 0, stream>>>(FL);
  k_mega<<<256, 1024, 0, stream>>>(x, W, amod, omod, tmod, dtp, srr, sim,
                                   traw, bb, sig, BA, FL, out);
}